// Round 6
// baseline (1199.069 us; speedup 1.0000x reference)
//
#include <hip/hip_runtime.h>
#include <hip/hip_fp16.h>

// GraphSAGE_GAT: SAGE(mean)x2 -> GAT(2 heads, softmax) -> edge MLP
// N=100000, E=1600000, D=32, H=2, EF=16.
// R6: 32-lane/node gat aggregate (one gather serves both heads);
//     byte-offset CSR (soff = src*64) kills per-gather addr arithmetic;
//     gat scores via precomputed c_s/c_d vectors, thread-per-node;
//     persistent grid-stride blocks amortize LDS weight staging.

#define DD 32
#define HH 2
#define EFF 16

__device__ __forceinline__ float lrelu(float x) { return x > 0.f ? x : 0.2f * x; }

// ---- CSR build: histogram of dst ----
__global__ void hist_k(const int* __restrict__ dst, int* __restrict__ deg, int E) {
    int e = blockIdx.x * blockDim.x + threadIdx.x;
    if (e < E) atomicAdd(&deg[dst[e]], 1);
}

// ---- scan phase 1: per-1024-chunk exclusive scan + chunk totals ----
__global__ void scan1_k(const int* __restrict__ deg, int* __restrict__ rowptr,
                        int* __restrict__ blockSums, int N) {
    __shared__ int s_s[256];
    int blk = blockIdx.x, t = threadIdx.x;
    int base = blk * 1024 + t * 4;
    int v[4];
    int s = 0;
#pragma unroll
    for (int i = 0; i < 4; i++) {
        v[i] = (base + i < N) ? deg[base + i] : 0;
        s += v[i];
    }
    s_s[t] = s;
    __syncthreads();
    for (int off = 1; off < 256; off <<= 1) {
        int x = (t >= off) ? s_s[t - off] : 0;
        __syncthreads();
        s_s[t] += x;
        __syncthreads();
    }
    int excl = s_s[t] - s;
#pragma unroll
    for (int i = 0; i < 4; i++) {
        if (base + i < N) rowptr[base + i] = excl;
        excl += v[i];
    }
    if (t == 255) blockSums[blk] = s_s[255];
}

// ---- scan phase 2: scan the chunk totals (<=128 chunks) ----
__global__ void scan2_k(int* __restrict__ blockSums, int* __restrict__ rowptrN, int NB) {
    __shared__ int s_s[128];
    int t = threadIdx.x;
    int v = (t < NB) ? blockSums[t] : 0;
    s_s[t] = v;
    __syncthreads();
    for (int off = 1; off < 128; off <<= 1) {
        int x = (t >= off) ? s_s[t - off] : 0;
        __syncthreads();
        s_s[t] += x;
        __syncthreads();
    }
    if (t < NB) blockSums[t] = s_s[t] - v;  // exclusive
    if (t == 127) *rowptrN = s_s[127];      // total = E
}

// ---- scan phase 3: add chunk offsets ----
__global__ void scan3_k(int* __restrict__ rowptr, const int* __restrict__ blockSums, int N) {
    int i = blockIdx.x * blockDim.x + threadIdx.x;
    if (i < N) rowptr[i] += blockSums[i >> 10];
}

// ---- CSR build: scatter byte offsets (src*64) + raw dst into buckets ----
__global__ void fill_k(const int* __restrict__ src, const int* __restrict__ dst,
                       const int* __restrict__ rowptr, int* __restrict__ fill,
                       int* __restrict__ soff, int* __restrict__ csr_dst, int E) {
    int e = blockIdx.x * blockDim.x + threadIdx.x;
    if (e >= E) return;
    int d = dst[e];
    int pos = rowptr[d] + atomicAdd(&fill[d], 1);
    soff[pos] = src[e] * 64;  // byte offset of a 64B fp16 row
    csr_dst[pos] = d;
}

// ---- convert fp32 -> fp16 ----
__global__ void cvt_k(const float* __restrict__ in, __half* __restrict__ out, int n) {
    int i = blockIdx.x * blockDim.x + threadIdx.x;
    if (i < n) out[i] = __float2half(in[i]);
}

// ---- SAGE fused: gather-mean + lin_l + lin_r + relu -> fp16 (persistent) ----
__global__ void sage_fused16(const __half* __restrict__ x, const int* __restrict__ rowptr,
                             const int* __restrict__ soff, const float* __restrict__ wl,
                             const float* __restrict__ bl, const float* __restrict__ wr,
                             __half* __restrict__ out, int N) {
    __shared__ float s_wl[DD * DD];
    __shared__ float s_wr[DD * DD];
    __shared__ float s_b[DD];
    for (int i = threadIdx.x; i < DD * DD; i += blockDim.x) {
        s_wl[i] = wl[i];
        s_wr[i] = wr[i];
    }
    if (threadIdx.x < DD) s_b[threadIdx.x] = bl[threadIdx.x];
    __syncthreads();
    int grp = threadIdx.x >> 5, k = threadIdx.x & 31;
    const char* xb = (const char*)x;
    for (int n = blockIdx.x * 8 + grp; n < N; n += gridDim.x * 8) {
        int lo = rowptr[n], hi = rowptr[n + 1];
        float a0 = 0.f, a1 = 0.f, a2 = 0.f, a3 = 0.f;
        int j = lo;
        for (; j + 3 < hi; j += 4) {
            int o0 = soff[j], o1 = soff[j + 1], o2 = soff[j + 2], o3 = soff[j + 3];
            a0 += __half2float(*(const __half*)(xb + o0 + k * 2));
            a1 += __half2float(*(const __half*)(xb + o1 + k * 2));
            a2 += __half2float(*(const __half*)(xb + o2 + k * 2));
            a3 += __half2float(*(const __half*)(xb + o3 + k * 2));
        }
        for (; j < hi; j++) a0 += __half2float(*(const __half*)(xb + soff[j] + k * 2));
        float mean = ((a0 + a1) + (a2 + a3)) / fmaxf((float)(hi - lo), 1.0f);
        float xv = __half2float(x[n * DD + k]);
        float o = s_b[k];
#pragma unroll
        for (int i = 0; i < DD; i++) {
            o += __shfl(mean, i, 32) * s_wl[i * DD + k];
            o += __shfl(xv, i, 32) * s_wr[i * DD + k];
        }
        out[n * DD + k] = __float2half(fmaxf(o, 0.f));
    }
}

// ---- c_s/c_d precompute: c4[i] = (W att_src)[i,h], (W att_dst)[i,h] ----
__global__ void prep_c_k(const float* __restrict__ w, const float* __restrict__ att_src,
                         const float* __restrict__ att_dst, float4* __restrict__ c4) {
    int i = threadIdx.x;
    if (i >= DD) return;
    float cs0 = 0.f, cs1 = 0.f, cd0 = 0.f, cd1 = 0.f;
    for (int d = 0; d < DD; d++) {
        float w0 = w[i * (HH * DD) + d], w1 = w[i * (HH * DD) + DD + d];
        cs0 += w0 * att_src[d];
        cs1 += w1 * att_src[DD + d];
        cd0 += w0 * att_dst[d];
        cd1 += w1 * att_dst[DD + d];
    }
    c4[i] = make_float4(cs0, cs1, cd0, cd1);
}

// ---- GAT scores: thread-per-node dot products against c_s/c_d ----
__global__ void gat_scores_v2(const __half* __restrict__ x2, const float4* __restrict__ c4,
                              float2* __restrict__ a_s, float2* __restrict__ a_d, int N) {
    __shared__ float4 s_c[DD];
    if (threadIdx.x < DD) s_c[threadIdx.x] = c4[threadIdx.x];
    __syncthreads();
    for (int n = blockIdx.x * blockDim.x + threadIdx.x; n < N; n += gridDim.x * blockDim.x) {
        const __half2* xr = (const __half2*)(x2 + (size_t)n * DD);
        float as0 = 0.f, as1 = 0.f, ad0 = 0.f, ad1 = 0.f;
#pragma unroll
        for (int i2 = 0; i2 < 16; i2++) {
            float2 f = __half22float2(xr[i2]);
            float4 ca = s_c[i2 * 2], cb = s_c[i2 * 2 + 1];
            as0 += f.x * ca.x + f.y * cb.x;
            as1 += f.x * ca.y + f.y * cb.y;
            ad0 += f.x * ca.z + f.y * cb.z;
            ad1 += f.x * ca.w + f.y * cb.w;
        }
        a_s[n] = make_float2(as0, as1);
        a_d[n] = make_float2(ad0, ad1);
    }
}

// ---- per-edge softmax weights (no max-sub; |alpha| small), CSR order ----
__global__ void edge_w_k(const int* __restrict__ soff, const int* __restrict__ csr_dst,
                         const float2* __restrict__ a_s, const float2* __restrict__ a_d,
                         __half2* __restrict__ ews, int E) {
    int e = blockIdx.x * blockDim.x + threadIdx.x;
    if (e >= E) return;
    int so = soff[e], d = csr_dst[e];
    float2 as = *(const float2*)((const char*)a_s + (so >> 3));  // s*8
    float2 ad = a_d[d];
    float w0 = __expf(lrelu(as.x + ad.x));
    float w1 = __expf(lrelu(as.y + ad.y));
    ews[e] = __floats2half2_rn(w0, w1);
}

// ---- GAT aggregate v5: 32 lanes/node, one gather serves both heads;
//      -> W transform -> head-mean+bias+relu -> fused mlp-pre (persistent) ----
__global__ void gat_agg_v5(const __half* __restrict__ x2, const float2* __restrict__ a_s,
                           const float2* __restrict__ a_d, const int* __restrict__ rowptr,
                           const int* __restrict__ soff, const __half2* __restrict__ ews,
                           const float* __restrict__ gw, const float* __restrict__ bias,
                           const float* __restrict__ w1, const float* __restrict__ b1,
                           __half* __restrict__ Ps, __half* __restrict__ Pd, int N) {
    __shared__ float s_gw[DD * HH * DD];  // gat W: 32 x 64
    __shared__ float s_w1[2 * DD * DD];   // mlp w1 rows 0..63
    __shared__ float s_b1[DD];
    __shared__ float s_bias[DD];
    int t = threadIdx.x;
    for (int i = t; i < DD * HH * DD; i += blockDim.x) s_gw[i] = gw[i];
    for (int i = t; i < 2 * DD * DD; i += blockDim.x) s_w1[i] = w1[i];
    if (t < DD) {
        s_b1[t] = b1[t];
        s_bias[t] = bias[t];
    }
    __syncthreads();
    int grp = t >> 5, kk = t & 31;
    const char* xb = (const char*)x2;
    for (int n = blockIdx.x * 8 + grp; n < N; n += gridDim.x * 8) {
        int lo = rowptr[n], hi = rowptr[n + 1];
        float2 as = a_s[n], ad = a_d[n];
        float ws0 = __expf(lrelu(as.x + ad.x));
        float ws1 = __expf(lrelu(as.y + ad.y));
        float xvs = __half2float(x2[n * DD + kk]);
        float den0 = ws0, den1 = ws1;
        float y0a = ws0 * xvs, y1a = ws1 * xvs;
        float y0b = 0.f, y1b = 0.f;
        int j = lo;
        for (; j + 3 < hi; j += 4) {
            int o0 = soff[j], o1 = soff[j + 1], o2 = soff[j + 2], o3 = soff[j + 3];
            float2 e0 = __half22float2(ews[j]);
            float2 e1 = __half22float2(ews[j + 1]);
            float2 e2 = __half22float2(ews[j + 2]);
            float2 e3 = __half22float2(ews[j + 3]);
            float xv0 = __half2float(*(const __half*)(xb + o0 + kk * 2));
            float xv1 = __half2float(*(const __half*)(xb + o1 + kk * 2));
            float xv2 = __half2float(*(const __half*)(xb + o2 + kk * 2));
            float xv3 = __half2float(*(const __half*)(xb + o3 + kk * 2));
            den0 += (e0.x + e1.x) + (e2.x + e3.x);
            den1 += (e0.y + e1.y) + (e2.y + e3.y);
            y0a += e0.x * xv0 + e2.x * xv2;
            y1a += e0.y * xv0 + e2.y * xv2;
            y0b += e1.x * xv1 + e3.x * xv3;
            y1b += e1.y * xv1 + e3.y * xv3;
        }
        for (; j < hi; j++) {
            int o0 = soff[j];
            float2 e0 = __half22float2(ews[j]);
            float xv0 = __half2float(*(const __half*)(xb + o0 + kk * 2));
            den0 += e0.x;
            den1 += e0.y;
            y0a += e0.x * xv0;
            y1a += e0.y * xv0;
        }
        float u0 = (y0a + y0b) / (den0 + 1e-16f);
        float u1 = (y1a + y1b) / (den1 + 1e-16f);
        // out[kk] = 0.5*(u0 @ Wg[:,kk] + u1 @ Wg[:,32+kk]) + bias, relu
        float o = 0.f;
#pragma unroll
        for (int i = 0; i < DD; i++) {
            float c0 = __shfl(u0, i, 32), c1 = __shfl(u1, i, 32);
            o += c0 * s_gw[i * (HH * DD) + kk] + c1 * s_gw[i * (HH * DD) + DD + kk];
        }
        o = fmaxf(0.5f * o + s_bias[kk], 0.f);
        // fused mlp-pre: Ps (rows 0..31 of w1, +b1), Pd (rows 32..63)
        float ps = s_b1[kk], pd = 0.f;
#pragma unroll
        for (int i = 0; i < DD; i++) {
            float oi = __shfl(o, i, 32);
            ps += oi * s_w1[i * DD + kk];
            pd += oi * s_w1[(DD + i) * DD + kk];
        }
        Ps[n * DD + kk] = __float2half(ps);
        Pd[n * DD + kk] = __float2half(pd);
    }
}

// ---- Edge MLP: acc = Ps[s] + Pd[d] + W1e*ea; out = relu(acc) . w2 + b2 ----
__device__ __forceinline__ void add_half_row(const __half* __restrict__ row, float acc[DD]) {
    const uint4* r4 = (const uint4*)row;
#pragma unroll
    for (int c = 0; c < 4; c++) {
        uint4 u = r4[c];
        unsigned uu[4] = {u.x, u.y, u.z, u.w};
#pragma unroll
        for (int t = 0; t < 4; t++) {
            __half2 h2 = *reinterpret_cast<const __half2*>(&uu[t]);
            float2 f = __half22float2(h2);
            acc[c * 8 + t * 2 + 0] += f.x;
            acc[c * 8 + t * 2 + 1] += f.y;
        }
    }
}

__global__ void edge_mlp_v3(const __half* __restrict__ Ps, const __half* __restrict__ Pd,
                            const float* __restrict__ eattr, const int* __restrict__ src,
                            const int* __restrict__ dst, const float* __restrict__ w1e,
                            const float* __restrict__ w2, const float* __restrict__ b2,
                            float* __restrict__ out, int E) {
    __shared__ float s_we[EFF * DD];  // rows 64..79 of w1
    __shared__ float s_w2[DD];
    for (int i = threadIdx.x; i < EFF * DD; i += blockDim.x) s_we[i] = w1e[i];
    if (threadIdx.x < DD) s_w2[threadIdx.x] = w2[threadIdx.x];
    __syncthreads();
    float b2v = b2[0];
    for (int e = blockIdx.x * blockDim.x + threadIdx.x; e < E; e += gridDim.x * blockDim.x) {
        int s = src[e], d = dst[e];
        float acc[DD] = {};
        add_half_row(Ps + (size_t)s * DD, acc);
        add_half_row(Pd + (size_t)d * DD, acc);
        const float4* ea4 = (const float4*)(eattr + (size_t)e * EFF);
#pragma unroll
        for (int c = 0; c < 4; c++) {
            float4 v = ea4[c];
            const float va[4] = {v.x, v.y, v.z, v.w};
#pragma unroll
            for (int r = 0; r < 4; r++) {
#pragma unroll
                for (int j4 = 0; j4 < 8; j4++) {
                    const float4 w = *(const float4*)(s_we + (c * 4 + r) * DD + j4 * 4);
                    acc[j4 * 4 + 0] += va[r] * w.x;
                    acc[j4 * 4 + 1] += va[r] * w.y;
                    acc[j4 * 4 + 2] += va[r] * w.z;
                    acc[j4 * 4 + 3] += va[r] * w.w;
                }
            }
        }
        float p = b2v;
#pragma unroll
        for (int j = 0; j < DD; j++) p += fmaxf(acc[j], 0.f) * s_w2[j];
        out[e] = p;
    }
}

extern "C" void kernel_launch(void* const* d_in, const int* in_sizes, int n_in,
                              void* d_out, int out_size, void* d_ws, size_t ws_size,
                              hipStream_t stream) {
    const int E = in_sizes[0] / 2;
    const int N = in_sizes[2] / DD;

    const int* src = (const int*)d_in[0];
    const int* dst = src + E;
    const float* edge_attr = (const float*)d_in[1];
    const float* node_emb = (const float*)d_in[2];
    const float* sage1_wl = (const float*)d_in[3];
    const float* sage1_bl = (const float*)d_in[4];
    const float* sage1_wr = (const float*)d_in[5];
    const float* sage2_wl = (const float*)d_in[6];
    const float* sage2_bl = (const float*)d_in[7];
    const float* sage2_wr = (const float*)d_in[8];
    const float* gat_w = (const float*)d_in[9];
    const float* gat_att_src = (const float*)d_in[10];
    const float* gat_att_dst = (const float*)d_in[11];
    const float* gat_bias = (const float*)d_in[12];
    const float* mlp_w1 = (const float*)d_in[13];
    const float* mlp_b1 = (const float*)d_in[14];
    const float* mlp_w2 = (const float*)d_in[15];
    const float* mlp_b2 = (const float*)d_in[16];
    float* out = (float*)d_out;

    // Workspace layout (256B-aligned chunks)
    char* ws = (char*)d_ws;
    size_t off = 0;
    auto alloc = [&](size_t bytes) {
        char* p = ws + off;
        off = (off + bytes + 255) & ~(size_t)255;
        return p;
    };
    int* deg = (int*)alloc((size_t)N * 4);
    int* rowptr = (int*)alloc((size_t)(N + 1) * 4);
    int* blockSums = (int*)alloc(128 * 4);
    int* soff = (int*)alloc((size_t)E * 4);
    int* csr_dst = (int*)alloc((size_t)E * 4);
    __half2* ews = (__half2*)alloc((size_t)E * 4);
    __half* x0h = (__half*)alloc((size_t)N * DD * 2);
    __half* x1h = (__half*)alloc((size_t)N * DD * 2);
    __half* x2h = (__half*)alloc((size_t)N * DD * 2);
    float2* a_s = (float2*)alloc((size_t)N * 8);
    float2* a_d = (float2*)alloc((size_t)N * 8);
    float4* c4 = (float4*)alloc(DD * 16);
    __half* Ps = (__half*)alloc((size_t)N * DD * 2);
    __half* Pd = (__half*)alloc((size_t)N * DD * 2);

    const int BS = 256;
    const int gE = (E + BS - 1) / BS;
    const int gN32 = (N * 32 + BS - 1) / BS;
    const int NB = (N + 1023) / 1024;
    const int GP = 2048;  // persistent grid for staged kernels
    const int gScores = min((N + BS - 1) / BS, 2048);
    const int gMlp = min(gE, 2048);

    // ---- CSR build ----
    hipMemsetAsync(deg, 0, (size_t)N * sizeof(int), stream);
    hist_k<<<gE, BS, 0, stream>>>(dst, deg, E);
    scan1_k<<<NB, 256, 0, stream>>>(deg, rowptr, blockSums, N);
    scan2_k<<<1, 128, 0, stream>>>(blockSums, rowptr + N, NB);
    scan3_k<<<(N + BS - 1) / BS, BS, 0, stream>>>(rowptr, blockSums, N);
    hipMemsetAsync(deg, 0, (size_t)N * sizeof(int), stream);
    fill_k<<<gE, BS, 0, stream>>>(src, dst, rowptr, deg, soff, csr_dst, E);

    // ---- fp16 input conversion ----
    cvt_k<<<gN32, BS, 0, stream>>>(node_emb, x0h, N * DD);

    // ---- SAGE layers ----
    sage_fused16<<<GP, BS, 0, stream>>>(x0h, rowptr, soff, sage1_wl, sage1_bl, sage1_wr,
                                        x1h, N);
    sage_fused16<<<GP, BS, 0, stream>>>(x1h, rowptr, soff, sage2_wl, sage2_bl, sage2_wr,
                                        x2h, N);

    // ---- GAT (+ fused mlp-pre) ----
    prep_c_k<<<1, 64, 0, stream>>>(gat_w, gat_att_src, gat_att_dst, c4);
    gat_scores_v2<<<gScores, BS, 0, stream>>>(x2h, c4, a_s, a_d, N);
    edge_w_k<<<gE, BS, 0, stream>>>(soff, csr_dst, a_s, a_d, ews, E);
    gat_agg_v5<<<GP, BS, 0, stream>>>(x2h, a_s, a_d, rowptr, soff, ews, gat_w, gat_bias,
                                      mlp_w1, mlp_b1, Ps, Pd, N);

    // ---- Edge MLP ----
    edge_mlp_v3<<<gMlp, BS, 0, stream>>>(Ps, Pd, edge_attr, src, dst,
                                         mlp_w1 + 2 * DD * DD, mlp_w2, mlp_b2, out, E);
}

// Round 7
// 678.998 us; speedup vs baseline: 1.7659x; 1.7659x over previous
//
#include <hip/hip_runtime.h>
#include <hip/hip_fp16.h>

// GraphSAGE_GAT: SAGE(mean)x2 -> GAT(2 heads, softmax) -> edge MLP
// N=100000, E=1600000, D=32, H=2, EF=16.
// R7: revert edge_mlp to bounded one-thread-per-edge (R6's grid-stride loop
//     spilled acc[32] to scratch: WRITE_SIZE 6.25->658 MB, 5x regression).
//     Keep R6's 32-lane gat_agg, byte-offset CSR, cheap scores, persistent sage.

#define DD 32
#define HH 2
#define EFF 16

__device__ __forceinline__ float lrelu(float x) { return x > 0.f ? x : 0.2f * x; }

// ---- CSR build: histogram of dst ----
__global__ void hist_k(const int* __restrict__ dst, int* __restrict__ deg, int E) {
    int e = blockIdx.x * blockDim.x + threadIdx.x;
    if (e < E) atomicAdd(&deg[dst[e]], 1);
}

// ---- scan phase 1: per-1024-chunk exclusive scan + chunk totals ----
__global__ void scan1_k(const int* __restrict__ deg, int* __restrict__ rowptr,
                        int* __restrict__ blockSums, int N) {
    __shared__ int s_s[256];
    int blk = blockIdx.x, t = threadIdx.x;
    int base = blk * 1024 + t * 4;
    int v[4];
    int s = 0;
#pragma unroll
    for (int i = 0; i < 4; i++) {
        v[i] = (base + i < N) ? deg[base + i] : 0;
        s += v[i];
    }
    s_s[t] = s;
    __syncthreads();
    for (int off = 1; off < 256; off <<= 1) {
        int x = (t >= off) ? s_s[t - off] : 0;
        __syncthreads();
        s_s[t] += x;
        __syncthreads();
    }
    int excl = s_s[t] - s;
#pragma unroll
    for (int i = 0; i < 4; i++) {
        if (base + i < N) rowptr[base + i] = excl;
        excl += v[i];
    }
    if (t == 255) blockSums[blk] = s_s[255];
}

// ---- scan phase 2: scan the chunk totals (<=128 chunks) ----
__global__ void scan2_k(int* __restrict__ blockSums, int* __restrict__ rowptrN, int NB) {
    __shared__ int s_s[128];
    int t = threadIdx.x;
    int v = (t < NB) ? blockSums[t] : 0;
    s_s[t] = v;
    __syncthreads();
    for (int off = 1; off < 128; off <<= 1) {
        int x = (t >= off) ? s_s[t - off] : 0;
        __syncthreads();
        s_s[t] += x;
        __syncthreads();
    }
    if (t < NB) blockSums[t] = s_s[t] - v;  // exclusive
    if (t == 127) *rowptrN = s_s[127];      // total = E
}

// ---- scan phase 3: add chunk offsets ----
__global__ void scan3_k(int* __restrict__ rowptr, const int* __restrict__ blockSums, int N) {
    int i = blockIdx.x * blockDim.x + threadIdx.x;
    if (i < N) rowptr[i] += blockSums[i >> 10];
}

// ---- CSR build: scatter byte offsets (src*64) + raw dst into buckets ----
__global__ void fill_k(const int* __restrict__ src, const int* __restrict__ dst,
                       const int* __restrict__ rowptr, int* __restrict__ fill,
                       int* __restrict__ soff, int* __restrict__ csr_dst, int E) {
    int e = blockIdx.x * blockDim.x + threadIdx.x;
    if (e >= E) return;
    int d = dst[e];
    int pos = rowptr[d] + atomicAdd(&fill[d], 1);
    soff[pos] = src[e] * 64;  // byte offset of a 64B fp16 row
    csr_dst[pos] = d;
}

// ---- convert fp32 -> fp16 ----
__global__ void cvt_k(const float* __restrict__ in, __half* __restrict__ out, int n) {
    int i = blockIdx.x * blockDim.x + threadIdx.x;
    if (i < n) out[i] = __float2half(in[i]);
}

// ---- SAGE fused: gather-mean + lin_l + lin_r + relu -> fp16 (persistent) ----
__global__ void sage_fused16(const __half* __restrict__ x, const int* __restrict__ rowptr,
                             const int* __restrict__ soff, const float* __restrict__ wl,
                             const float* __restrict__ bl, const float* __restrict__ wr,
                             __half* __restrict__ out, int N) {
    __shared__ float s_wl[DD * DD];
    __shared__ float s_wr[DD * DD];
    __shared__ float s_b[DD];
    for (int i = threadIdx.x; i < DD * DD; i += blockDim.x) {
        s_wl[i] = wl[i];
        s_wr[i] = wr[i];
    }
    if (threadIdx.x < DD) s_b[threadIdx.x] = bl[threadIdx.x];
    __syncthreads();
    int grp = threadIdx.x >> 5, k = threadIdx.x & 31;
    const char* xb = (const char*)x;
    for (int n = blockIdx.x * 8 + grp; n < N; n += gridDim.x * 8) {
        int lo = rowptr[n], hi = rowptr[n + 1];
        float a0 = 0.f, a1 = 0.f, a2 = 0.f, a3 = 0.f;
        int j = lo;
        for (; j + 3 < hi; j += 4) {
            int o0 = soff[j], o1 = soff[j + 1], o2 = soff[j + 2], o3 = soff[j + 3];
            a0 += __half2float(*(const __half*)(xb + o0 + k * 2));
            a1 += __half2float(*(const __half*)(xb + o1 + k * 2));
            a2 += __half2float(*(const __half*)(xb + o2 + k * 2));
            a3 += __half2float(*(const __half*)(xb + o3 + k * 2));
        }
        for (; j < hi; j++) a0 += __half2float(*(const __half*)(xb + soff[j] + k * 2));
        float mean = ((a0 + a1) + (a2 + a3)) / fmaxf((float)(hi - lo), 1.0f);
        float xv = __half2float(x[n * DD + k]);
        float o = s_b[k];
#pragma unroll
        for (int i = 0; i < DD; i++) {
            o += __shfl(mean, i, 32) * s_wl[i * DD + k];
            o += __shfl(xv, i, 32) * s_wr[i * DD + k];
        }
        out[n * DD + k] = __float2half(fmaxf(o, 0.f));
    }
}

// ---- c_s/c_d precompute: c4[i] = (W att_src)[i,h], (W att_dst)[i,h] ----
__global__ void prep_c_k(const float* __restrict__ w, const float* __restrict__ att_src,
                         const float* __restrict__ att_dst, float4* __restrict__ c4) {
    int i = threadIdx.x;
    if (i >= DD) return;
    float cs0 = 0.f, cs1 = 0.f, cd0 = 0.f, cd1 = 0.f;
    for (int d = 0; d < DD; d++) {
        float w0 = w[i * (HH * DD) + d], w1 = w[i * (HH * DD) + DD + d];
        cs0 += w0 * att_src[d];
        cs1 += w1 * att_src[DD + d];
        cd0 += w0 * att_dst[d];
        cd1 += w1 * att_dst[DD + d];
    }
    c4[i] = make_float4(cs0, cs1, cd0, cd1);
}

// ---- GAT scores: thread-per-node dot products against c_s/c_d ----
__global__ void gat_scores_v2(const __half* __restrict__ x2, const float4* __restrict__ c4,
                              float2* __restrict__ a_s, float2* __restrict__ a_d, int N) {
    __shared__ float4 s_c[DD];
    if (threadIdx.x < DD) s_c[threadIdx.x] = c4[threadIdx.x];
    __syncthreads();
    for (int n = blockIdx.x * blockDim.x + threadIdx.x; n < N; n += gridDim.x * blockDim.x) {
        const __half2* xr = (const __half2*)(x2 + (size_t)n * DD);
        float as0 = 0.f, as1 = 0.f, ad0 = 0.f, ad1 = 0.f;
#pragma unroll
        for (int i2 = 0; i2 < 16; i2++) {
            float2 f = __half22float2(xr[i2]);
            float4 ca = s_c[i2 * 2], cb = s_c[i2 * 2 + 1];
            as0 += f.x * ca.x + f.y * cb.x;
            as1 += f.x * ca.y + f.y * cb.y;
            ad0 += f.x * ca.z + f.y * cb.z;
            ad1 += f.x * ca.w + f.y * cb.w;
        }
        a_s[n] = make_float2(as0, as1);
        a_d[n] = make_float2(ad0, ad1);
    }
}

// ---- per-edge softmax weights (no max-sub; |alpha| small), CSR order ----
__global__ void edge_w_k(const int* __restrict__ soff, const int* __restrict__ csr_dst,
                         const float2* __restrict__ a_s, const float2* __restrict__ a_d,
                         __half2* __restrict__ ews, int E) {
    int e = blockIdx.x * blockDim.x + threadIdx.x;
    if (e >= E) return;
    int so = soff[e], d = csr_dst[e];
    float2 as = *(const float2*)((const char*)a_s + (so >> 3));  // s*8
    float2 ad = a_d[d];
    float w0 = __expf(lrelu(as.x + ad.x));
    float w1 = __expf(lrelu(as.y + ad.y));
    ews[e] = __floats2half2_rn(w0, w1);
}

// ---- GAT aggregate v5: 32 lanes/node, one gather serves both heads;
//      -> W transform -> head-mean+bias+relu -> fused mlp-pre (persistent) ----
__global__ void gat_agg_v5(const __half* __restrict__ x2, const float2* __restrict__ a_s,
                           const float2* __restrict__ a_d, const int* __restrict__ rowptr,
                           const int* __restrict__ soff, const __half2* __restrict__ ews,
                           const float* __restrict__ gw, const float* __restrict__ bias,
                           const float* __restrict__ w1, const float* __restrict__ b1,
                           __half* __restrict__ Ps, __half* __restrict__ Pd, int N) {
    __shared__ float s_gw[DD * HH * DD];  // gat W: 32 x 64
    __shared__ float s_w1[2 * DD * DD];   // mlp w1 rows 0..63
    __shared__ float s_b1[DD];
    __shared__ float s_bias[DD];
    int t = threadIdx.x;
    for (int i = t; i < DD * HH * DD; i += blockDim.x) s_gw[i] = gw[i];
    for (int i = t; i < 2 * DD * DD; i += blockDim.x) s_w1[i] = w1[i];
    if (t < DD) {
        s_b1[t] = b1[t];
        s_bias[t] = bias[t];
    }
    __syncthreads();
    int grp = t >> 5, kk = t & 31;
    const char* xb = (const char*)x2;
    for (int n = blockIdx.x * 8 + grp; n < N; n += gridDim.x * 8) {
        int lo = rowptr[n], hi = rowptr[n + 1];
        float2 as = a_s[n], ad = a_d[n];
        float ws0 = __expf(lrelu(as.x + ad.x));
        float ws1 = __expf(lrelu(as.y + ad.y));
        float xvs = __half2float(x2[n * DD + kk]);
        float den0 = ws0, den1 = ws1;
        float y0a = ws0 * xvs, y1a = ws1 * xvs;
        float y0b = 0.f, y1b = 0.f;
        int j = lo;
        for (; j + 3 < hi; j += 4) {
            int o0 = soff[j], o1 = soff[j + 1], o2 = soff[j + 2], o3 = soff[j + 3];
            float2 e0 = __half22float2(ews[j]);
            float2 e1 = __half22float2(ews[j + 1]);
            float2 e2 = __half22float2(ews[j + 2]);
            float2 e3 = __half22float2(ews[j + 3]);
            float xv0 = __half2float(*(const __half*)(xb + o0 + kk * 2));
            float xv1 = __half2float(*(const __half*)(xb + o1 + kk * 2));
            float xv2 = __half2float(*(const __half*)(xb + o2 + kk * 2));
            float xv3 = __half2float(*(const __half*)(xb + o3 + kk * 2));
            den0 += (e0.x + e1.x) + (e2.x + e3.x);
            den1 += (e0.y + e1.y) + (e2.y + e3.y);
            y0a += e0.x * xv0 + e2.x * xv2;
            y1a += e0.y * xv0 + e2.y * xv2;
            y0b += e1.x * xv1 + e3.x * xv3;
            y1b += e1.y * xv1 + e3.y * xv3;
        }
        for (; j < hi; j++) {
            int o0 = soff[j];
            float2 e0 = __half22float2(ews[j]);
            float xv0 = __half2float(*(const __half*)(xb + o0 + kk * 2));
            den0 += e0.x;
            den1 += e0.y;
            y0a += e0.x * xv0;
            y1a += e0.y * xv0;
        }
        float u0 = (y0a + y0b) / (den0 + 1e-16f);
        float u1 = (y1a + y1b) / (den1 + 1e-16f);
        // out[kk] = 0.5*(u0 @ Wg[:,kk] + u1 @ Wg[:,32+kk]) + bias, relu
        float o = 0.f;
#pragma unroll
        for (int i = 0; i < DD; i++) {
            float c0 = __shfl(u0, i, 32), c1 = __shfl(u1, i, 32);
            o += c0 * s_gw[i * (HH * DD) + kk] + c1 * s_gw[i * (HH * DD) + DD + kk];
        }
        o = fmaxf(0.5f * o + s_bias[kk], 0.f);
        // fused mlp-pre: Ps (rows 0..31 of w1, +b1), Pd (rows 32..63)
        float ps = s_b1[kk], pd = 0.f;
#pragma unroll
        for (int i = 0; i < DD; i++) {
            float oi = __shfl(o, i, 32);
            ps += oi * s_w1[i * DD + kk];
            pd += oi * s_w1[(DD + i) * DD + kk];
        }
        Ps[n * DD + kk] = __float2half(ps);
        Pd[n * DD + kk] = __float2half(pd);
    }
}

// ---- Edge MLP: acc = Ps[s] + Pd[d] + W1e*ea; out = relu(acc) . w2 + b2 ----
// one thread per edge, straight-line body (NO grid-stride: R6's loop spilled
// acc[32] to scratch -> 658MB scratch writes, 5x regression)
__device__ __forceinline__ void add_half_row(const __half* __restrict__ row, float acc[DD]) {
    const uint4* r4 = (const uint4*)row;
#pragma unroll
    for (int c = 0; c < 4; c++) {
        uint4 u = r4[c];
        unsigned uu[4] = {u.x, u.y, u.z, u.w};
#pragma unroll
        for (int t = 0; t < 4; t++) {
            __half2 h2 = *reinterpret_cast<const __half2*>(&uu[t]);
            float2 f = __half22float2(h2);
            acc[c * 8 + t * 2 + 0] += f.x;
            acc[c * 8 + t * 2 + 1] += f.y;
        }
    }
}

__global__ void edge_mlp_v3(const __half* __restrict__ Ps, const __half* __restrict__ Pd,
                            const float* __restrict__ eattr, const int* __restrict__ src,
                            const int* __restrict__ dst, const float* __restrict__ w1e,
                            const float* __restrict__ w2, const float* __restrict__ b2,
                            float* __restrict__ out, int E) {
    __shared__ float s_we[EFF * DD];  // rows 64..79 of w1
    __shared__ float s_w2[DD];
    for (int i = threadIdx.x; i < EFF * DD; i += blockDim.x) s_we[i] = w1e[i];
    if (threadIdx.x < DD) s_w2[threadIdx.x] = w2[threadIdx.x];
    __syncthreads();
    int e = blockIdx.x * blockDim.x + threadIdx.x;
    if (e >= E) return;
    float b2v = b2[0];
    int s = src[e], d = dst[e];
    float acc[DD] = {};
    add_half_row(Ps + (size_t)s * DD, acc);
    add_half_row(Pd + (size_t)d * DD, acc);
    const float4* ea4 = (const float4*)(eattr + (size_t)e * EFF);
#pragma unroll
    for (int c = 0; c < 4; c++) {
        float4 v = ea4[c];
        const float va[4] = {v.x, v.y, v.z, v.w};
#pragma unroll
        for (int r = 0; r < 4; r++) {
#pragma unroll
            for (int j4 = 0; j4 < 8; j4++) {
                const float4 w = *(const float4*)(s_we + (c * 4 + r) * DD + j4 * 4);
                acc[j4 * 4 + 0] += va[r] * w.x;
                acc[j4 * 4 + 1] += va[r] * w.y;
                acc[j4 * 4 + 2] += va[r] * w.z;
                acc[j4 * 4 + 3] += va[r] * w.w;
            }
        }
    }
    float p = b2v;
#pragma unroll
    for (int j = 0; j < DD; j++) p += fmaxf(acc[j], 0.f) * s_w2[j];
    out[e] = p;
}

extern "C" void kernel_launch(void* const* d_in, const int* in_sizes, int n_in,
                              void* d_out, int out_size, void* d_ws, size_t ws_size,
                              hipStream_t stream) {
    const int E = in_sizes[0] / 2;
    const int N = in_sizes[2] / DD;

    const int* src = (const int*)d_in[0];
    const int* dst = src + E;
    const float* edge_attr = (const float*)d_in[1];
    const float* node_emb = (const float*)d_in[2];
    const float* sage1_wl = (const float*)d_in[3];
    const float* sage1_bl = (const float*)d_in[4];
    const float* sage1_wr = (const float*)d_in[5];
    const float* sage2_wl = (const float*)d_in[6];
    const float* sage2_bl = (const float*)d_in[7];
    const float* sage2_wr = (const float*)d_in[8];
    const float* gat_w = (const float*)d_in[9];
    const float* gat_att_src = (const float*)d_in[10];
    const float* gat_att_dst = (const float*)d_in[11];
    const float* gat_bias = (const float*)d_in[12];
    const float* mlp_w1 = (const float*)d_in[13];
    const float* mlp_b1 = (const float*)d_in[14];
    const float* mlp_w2 = (const float*)d_in[15];
    const float* mlp_b2 = (const float*)d_in[16];
    float* out = (float*)d_out;

    // Workspace layout (256B-aligned chunks)
    char* ws = (char*)d_ws;
    size_t off = 0;
    auto alloc = [&](size_t bytes) {
        char* p = ws + off;
        off = (off + bytes + 255) & ~(size_t)255;
        return p;
    };
    int* deg = (int*)alloc((size_t)N * 4);
    int* rowptr = (int*)alloc((size_t)(N + 1) * 4);
    int* blockSums = (int*)alloc(128 * 4);
    int* soff = (int*)alloc((size_t)E * 4);
    int* csr_dst = (int*)alloc((size_t)E * 4);
    __half2* ews = (__half2*)alloc((size_t)E * 4);
    __half* x0h = (__half*)alloc((size_t)N * DD * 2);
    __half* x1h = (__half*)alloc((size_t)N * DD * 2);
    __half* x2h = (__half*)alloc((size_t)N * DD * 2);
    float2* a_s = (float2*)alloc((size_t)N * 8);
    float2* a_d = (float2*)alloc((size_t)N * 8);
    float4* c4 = (float4*)alloc(DD * 16);
    __half* Ps = (__half*)alloc((size_t)N * DD * 2);
    __half* Pd = (__half*)alloc((size_t)N * DD * 2);

    const int BS = 256;
    const int gE = (E + BS - 1) / BS;
    const int gN32 = (N * 32 + BS - 1) / BS;
    const int NB = (N + 1023) / 1024;
    const int GP = 2048;  // persistent grid for staged node kernels
    const int gScores = min((N + BS - 1) / BS, 2048);

    // ---- CSR build ----
    hipMemsetAsync(deg, 0, (size_t)N * sizeof(int), stream);
    hist_k<<<gE, BS, 0, stream>>>(dst, deg, E);
    scan1_k<<<NB, 256, 0, stream>>>(deg, rowptr, blockSums, N);
    scan2_k<<<1, 128, 0, stream>>>(blockSums, rowptr + N, NB);
    scan3_k<<<(N + BS - 1) / BS, BS, 0, stream>>>(rowptr, blockSums, N);
    hipMemsetAsync(deg, 0, (size_t)N * sizeof(int), stream);
    fill_k<<<gE, BS, 0, stream>>>(src, dst, rowptr, deg, soff, csr_dst, E);

    // ---- fp16 input conversion ----
    cvt_k<<<gN32, BS, 0, stream>>>(node_emb, x0h, N * DD);

    // ---- SAGE layers ----
    sage_fused16<<<GP, BS, 0, stream>>>(x0h, rowptr, soff, sage1_wl, sage1_bl, sage1_wr,
                                        x1h, N);
    sage_fused16<<<GP, BS, 0, stream>>>(x1h, rowptr, soff, sage2_wl, sage2_bl, sage2_wr,
                                        x2h, N);

    // ---- GAT (+ fused mlp-pre) ----
    prep_c_k<<<1, 64, 0, stream>>>(gat_w, gat_att_src, gat_att_dst, c4);
    gat_scores_v2<<<gScores, BS, 0, stream>>>(x2h, c4, a_s, a_d, N);
    edge_w_k<<<gE, BS, 0, stream>>>(soff, csr_dst, a_s, a_d, ews, E);
    gat_agg_v5<<<GP, BS, 0, stream>>>(x2h, a_s, a_d, rowptr, soff, ews, gat_w, gat_bias,
                                      mlp_w1, mlp_b1, Ps, Pd, N);

    // ---- Edge MLP ----
    edge_mlp_v3<<<gE, BS, 0, stream>>>(Ps, Pd, edge_attr, src, dst,
                                       mlp_w1 + 2 * DD * DD, mlp_w2, mlp_b2, out, E);
}

// Round 8
// 558.654 us; speedup vs baseline: 2.1464x; 1.2154x over previous
//
#include <hip/hip_runtime.h>
#include <hip/hip_fp16.h>

// GraphSAGE_GAT: SAGE(mean)x2 -> GAT(2 heads, softmax) -> edge MLP
// N=100000, E=1600000, D=32, H=2, EF=16.
// R8: ALL node kernels on bounded grids with straight-line bodies.
//     (R6/R7 lesson: persistent grid-stride loops made the compiler spill
//      loop-carried state to scratch: gat_agg VGPR 28->64, WRITE 12->115MB,
//      FETCH 69->410MB. Bounded grids + per-block LDS staging is cheaper.)
//     Keep: 32-lane/node gat aggregate (2 nodes/wave), byte-offset CSR,
//     c_s/c_d precomputed scores, fused mlp-pre in gat epilogue.

#define DD 32
#define HH 2
#define EFF 16

__device__ __forceinline__ float lrelu(float x) { return x > 0.f ? x : 0.2f * x; }

// ---- CSR build: histogram of dst ----
__global__ void hist_k(const int* __restrict__ dst, int* __restrict__ deg, int E) {
    int e = blockIdx.x * blockDim.x + threadIdx.x;
    if (e < E) atomicAdd(&deg[dst[e]], 1);
}

// ---- scan phase 1: per-1024-chunk exclusive scan + chunk totals ----
__global__ void scan1_k(const int* __restrict__ deg, int* __restrict__ rowptr,
                        int* __restrict__ blockSums, int N) {
    __shared__ int s_s[256];
    int blk = blockIdx.x, t = threadIdx.x;
    int base = blk * 1024 + t * 4;
    int v[4];
    int s = 0;
#pragma unroll
    for (int i = 0; i < 4; i++) {
        v[i] = (base + i < N) ? deg[base + i] : 0;
        s += v[i];
    }
    s_s[t] = s;
    __syncthreads();
    for (int off = 1; off < 256; off <<= 1) {
        int x = (t >= off) ? s_s[t - off] : 0;
        __syncthreads();
        s_s[t] += x;
        __syncthreads();
    }
    int excl = s_s[t] - s;
#pragma unroll
    for (int i = 0; i < 4; i++) {
        if (base + i < N) rowptr[base + i] = excl;
        excl += v[i];
    }
    if (t == 255) blockSums[blk] = s_s[255];
}

// ---- scan phase 2: scan the chunk totals (<=128 chunks) ----
__global__ void scan2_k(int* __restrict__ blockSums, int* __restrict__ rowptrN, int NB) {
    __shared__ int s_s[128];
    int t = threadIdx.x;
    int v = (t < NB) ? blockSums[t] : 0;
    s_s[t] = v;
    __syncthreads();
    for (int off = 1; off < 128; off <<= 1) {
        int x = (t >= off) ? s_s[t - off] : 0;
        __syncthreads();
        s_s[t] += x;
        __syncthreads();
    }
    if (t < NB) blockSums[t] = s_s[t] - v;  // exclusive
    if (t == 127) *rowptrN = s_s[127];      // total = E
}

// ---- scan phase 3: add chunk offsets ----
__global__ void scan3_k(int* __restrict__ rowptr, const int* __restrict__ blockSums, int N) {
    int i = blockIdx.x * blockDim.x + threadIdx.x;
    if (i < N) rowptr[i] += blockSums[i >> 10];
}

// ---- CSR build: scatter byte offsets (src*64) + raw dst into buckets ----
__global__ void fill_k(const int* __restrict__ src, const int* __restrict__ dst,
                       const int* __restrict__ rowptr, int* __restrict__ fill,
                       int* __restrict__ soff, int* __restrict__ csr_dst, int E) {
    int e = blockIdx.x * blockDim.x + threadIdx.x;
    if (e >= E) return;
    int d = dst[e];
    int pos = rowptr[d] + atomicAdd(&fill[d], 1);
    soff[pos] = src[e] * 64;  // byte offset of a 64B fp16 row
    csr_dst[pos] = d;
}

// ---- convert fp32 -> fp16 ----
__global__ void cvt_k(const float* __restrict__ in, __half* __restrict__ out, int n) {
    int i = blockIdx.x * blockDim.x + threadIdx.x;
    if (i < n) out[i] = __float2half(in[i]);
}

// ---- SAGE fused: gather-mean + lin_l + lin_r + relu -> fp16 (bounded) ----
// one 32-lane group per node
__global__ void sage_fused16(const __half* __restrict__ x, const int* __restrict__ rowptr,
                             const int* __restrict__ soff, const float* __restrict__ wl,
                             const float* __restrict__ bl, const float* __restrict__ wr,
                             __half* __restrict__ out, int N) {
    __shared__ float s_wl[DD * DD];
    __shared__ float s_wr[DD * DD];
    __shared__ float s_b[DD];
    for (int i = threadIdx.x; i < DD * DD; i += blockDim.x) {
        s_wl[i] = wl[i];
        s_wr[i] = wr[i];
    }
    if (threadIdx.x < DD) s_b[threadIdx.x] = bl[threadIdx.x];
    __syncthreads();
    int gid = blockIdx.x * blockDim.x + threadIdx.x;
    int n = gid >> 5;
    if (n >= N) return;
    int k = gid & 31;
    int lo = rowptr[n], hi = rowptr[n + 1];
    const char* xb = (const char*)x;
    float a0 = 0.f, a1 = 0.f, a2 = 0.f, a3 = 0.f;
    int j = lo;
    for (; j + 3 < hi; j += 4) {
        int o0 = soff[j], o1 = soff[j + 1], o2 = soff[j + 2], o3 = soff[j + 3];
        a0 += __half2float(*(const __half*)(xb + o0 + k * 2));
        a1 += __half2float(*(const __half*)(xb + o1 + k * 2));
        a2 += __half2float(*(const __half*)(xb + o2 + k * 2));
        a3 += __half2float(*(const __half*)(xb + o3 + k * 2));
    }
    for (; j < hi; j++) a0 += __half2float(*(const __half*)(xb + soff[j] + k * 2));
    float mean = ((a0 + a1) + (a2 + a3)) / fmaxf((float)(hi - lo), 1.0f);
    float xv = __half2float(x[n * DD + k]);
    float o = s_b[k];
#pragma unroll
    for (int i = 0; i < DD; i++) {
        o += __shfl(mean, i, 32) * s_wl[i * DD + k];
        o += __shfl(xv, i, 32) * s_wr[i * DD + k];
    }
    out[n * DD + k] = __float2half(fmaxf(o, 0.f));
}

// ---- c_s/c_d precompute: c4[i] = (W att_src)[i,h], (W att_dst)[i,h] ----
__global__ void prep_c_k(const float* __restrict__ w, const float* __restrict__ att_src,
                         const float* __restrict__ att_dst, float4* __restrict__ c4) {
    int i = threadIdx.x;
    if (i >= DD) return;
    float cs0 = 0.f, cs1 = 0.f, cd0 = 0.f, cd1 = 0.f;
    for (int d = 0; d < DD; d++) {
        float w0 = w[i * (HH * DD) + d], w1 = w[i * (HH * DD) + DD + d];
        cs0 += w0 * att_src[d];
        cs1 += w1 * att_src[DD + d];
        cd0 += w0 * att_dst[d];
        cd1 += w1 * att_dst[DD + d];
    }
    c4[i] = make_float4(cs0, cs1, cd0, cd1);
}

// ---- GAT scores: thread-per-node dot products against c_s/c_d (bounded) ----
__global__ void gat_scores_v2(const __half* __restrict__ x2, const float4* __restrict__ c4,
                              float2* __restrict__ a_s, float2* __restrict__ a_d, int N) {
    __shared__ float4 s_c[DD];
    if (threadIdx.x < DD) s_c[threadIdx.x] = c4[threadIdx.x];
    __syncthreads();
    int n = blockIdx.x * blockDim.x + threadIdx.x;
    if (n >= N) return;
    const __half2* xr = (const __half2*)(x2 + (size_t)n * DD);
    float as0 = 0.f, as1 = 0.f, ad0 = 0.f, ad1 = 0.f;
#pragma unroll
    for (int i2 = 0; i2 < 16; i2++) {
        float2 f = __half22float2(xr[i2]);
        float4 ca = s_c[i2 * 2], cb = s_c[i2 * 2 + 1];
        as0 += f.x * ca.x + f.y * cb.x;
        as1 += f.x * ca.y + f.y * cb.y;
        ad0 += f.x * ca.z + f.y * cb.z;
        ad1 += f.x * ca.w + f.y * cb.w;
    }
    a_s[n] = make_float2(as0, as1);
    a_d[n] = make_float2(ad0, ad1);
}

// ---- per-edge softmax weights (no max-sub; |alpha| small), CSR order ----
__global__ void edge_w_k(const int* __restrict__ soff, const int* __restrict__ csr_dst,
                         const float2* __restrict__ a_s, const float2* __restrict__ a_d,
                         __half2* __restrict__ ews, int E) {
    int e = blockIdx.x * blockDim.x + threadIdx.x;
    if (e >= E) return;
    int so = soff[e], d = csr_dst[e];
    float2 as = *(const float2*)((const char*)a_s + (so >> 3));  // s*8
    float2 ad = a_d[d];
    float w0 = __expf(lrelu(as.x + ad.x));
    float w1 = __expf(lrelu(as.y + ad.y));
    ews[e] = __floats2half2_rn(w0, w1);
}

// ---- GAT aggregate v6: 32 lanes/node (2 nodes/wave), bounded grid;
//      one gather serves both heads -> W transform -> head-mean+bias+relu
//      -> fused mlp-pre ----
__global__ void gat_agg_v6(const __half* __restrict__ x2, const float2* __restrict__ a_s,
                           const float2* __restrict__ a_d, const int* __restrict__ rowptr,
                           const int* __restrict__ soff, const __half2* __restrict__ ews,
                           const float* __restrict__ gw, const float* __restrict__ bias,
                           const float* __restrict__ w1, const float* __restrict__ b1,
                           __half* __restrict__ Ps, __half* __restrict__ Pd, int N) {
    __shared__ float s_gw[DD * HH * DD];  // gat W: 32 x 64
    __shared__ float s_w1[2 * DD * DD];   // mlp w1 rows 0..63
    __shared__ float s_b1[DD];
    __shared__ float s_bias[DD];
    int t = threadIdx.x;
    for (int i = t; i < DD * HH * DD; i += blockDim.x) s_gw[i] = gw[i];
    for (int i = t; i < 2 * DD * DD; i += blockDim.x) s_w1[i] = w1[i];
    if (t < DD) {
        s_b1[t] = b1[t];
        s_bias[t] = bias[t];
    }
    __syncthreads();
    int gid = blockIdx.x * blockDim.x + t;
    int n = gid >> 5;
    if (n >= N) return;
    int kk = gid & 31;
    const char* xb = (const char*)x2;
    int lo = rowptr[n], hi = rowptr[n + 1];
    float2 as = a_s[n], ad = a_d[n];
    float ws0 = __expf(lrelu(as.x + ad.x));
    float ws1 = __expf(lrelu(as.y + ad.y));
    float xvs = __half2float(x2[n * DD + kk]);
    float den0 = ws0, den1 = ws1;
    float y0a = ws0 * xvs, y1a = ws1 * xvs;
    float y0b = 0.f, y1b = 0.f;
    int j = lo;
    for (; j + 3 < hi; j += 4) {
        int o0 = soff[j], o1 = soff[j + 1], o2 = soff[j + 2], o3 = soff[j + 3];
        float2 e0 = __half22float2(ews[j]);
        float2 e1 = __half22float2(ews[j + 1]);
        float2 e2 = __half22float2(ews[j + 2]);
        float2 e3 = __half22float2(ews[j + 3]);
        float xv0 = __half2float(*(const __half*)(xb + o0 + kk * 2));
        float xv1 = __half2float(*(const __half*)(xb + o1 + kk * 2));
        float xv2 = __half2float(*(const __half*)(xb + o2 + kk * 2));
        float xv3 = __half2float(*(const __half*)(xb + o3 + kk * 2));
        den0 += (e0.x + e1.x) + (e2.x + e3.x);
        den1 += (e0.y + e1.y) + (e2.y + e3.y);
        y0a += e0.x * xv0 + e2.x * xv2;
        y1a += e0.y * xv0 + e2.y * xv2;
        y0b += e1.x * xv1 + e3.x * xv3;
        y1b += e1.y * xv1 + e3.y * xv3;
    }
    for (; j < hi; j++) {
        int o0 = soff[j];
        float2 e0 = __half22float2(ews[j]);
        float xv0 = __half2float(*(const __half*)(xb + o0 + kk * 2));
        den0 += e0.x;
        den1 += e0.y;
        y0a += e0.x * xv0;
        y1a += e0.y * xv0;
    }
    float u0 = (y0a + y0b) / (den0 + 1e-16f);
    float u1 = (y1a + y1b) / (den1 + 1e-16f);
    // out[kk] = 0.5*(u0 @ Wg[:,kk] + u1 @ Wg[:,32+kk]) + bias, relu
    float o = 0.f;
#pragma unroll
    for (int i = 0; i < DD; i++) {
        float c0 = __shfl(u0, i, 32), c1 = __shfl(u1, i, 32);
        o += c0 * s_gw[i * (HH * DD) + kk] + c1 * s_gw[i * (HH * DD) + DD + kk];
    }
    o = fmaxf(0.5f * o + s_bias[kk], 0.f);
    // fused mlp-pre: Ps (rows 0..31 of w1, +b1), Pd (rows 32..63)
    float ps = s_b1[kk], pd = 0.f;
#pragma unroll
    for (int i = 0; i < DD; i++) {
        float oi = __shfl(o, i, 32);
        ps += oi * s_w1[i * DD + kk];
        pd += oi * s_w1[(DD + i) * DD + kk];
    }
    Ps[n * DD + kk] = __float2half(ps);
    Pd[n * DD + kk] = __float2half(pd);
}

// ---- Edge MLP: acc = Ps[s] + Pd[d] + W1e*ea; out = relu(acc) . w2 + b2 ----
// one thread per edge, straight-line body
__device__ __forceinline__ void add_half_row(const __half* __restrict__ row, float acc[DD]) {
    const uint4* r4 = (const uint4*)row;
#pragma unroll
    for (int c = 0; c < 4; c++) {
        uint4 u = r4[c];
        unsigned uu[4] = {u.x, u.y, u.z, u.w};
#pragma unroll
        for (int t = 0; t < 4; t++) {
            __half2 h2 = *reinterpret_cast<const __half2*>(&uu[t]);
            float2 f = __half22float2(h2);
            acc[c * 8 + t * 2 + 0] += f.x;
            acc[c * 8 + t * 2 + 1] += f.y;
        }
    }
}

__global__ void edge_mlp_v3(const __half* __restrict__ Ps, const __half* __restrict__ Pd,
                            const float* __restrict__ eattr, const int* __restrict__ src,
                            const int* __restrict__ dst, const float* __restrict__ w1e,
                            const float* __restrict__ w2, const float* __restrict__ b2,
                            float* __restrict__ out, int E) {
    __shared__ float s_we[EFF * DD];  // rows 64..79 of w1
    __shared__ float s_w2[DD];
    for (int i = threadIdx.x; i < EFF * DD; i += blockDim.x) s_we[i] = w1e[i];
    if (threadIdx.x < DD) s_w2[threadIdx.x] = w2[threadIdx.x];
    __syncthreads();
    int e = blockIdx.x * blockDim.x + threadIdx.x;
    if (e >= E) return;
    float b2v = b2[0];
    int s = src[e], d = dst[e];
    float acc[DD] = {};
    add_half_row(Ps + (size_t)s * DD, acc);
    add_half_row(Pd + (size_t)d * DD, acc);
    const float4* ea4 = (const float4*)(eattr + (size_t)e * EFF);
#pragma unroll
    for (int c = 0; c < 4; c++) {
        float4 v = ea4[c];
        const float va[4] = {v.x, v.y, v.z, v.w};
#pragma unroll
        for (int r = 0; r < 4; r++) {
#pragma unroll
            for (int j4 = 0; j4 < 8; j4++) {
                const float4 w = *(const float4*)(s_we + (c * 4 + r) * DD + j4 * 4);
                acc[j4 * 4 + 0] += va[r] * w.x;
                acc[j4 * 4 + 1] += va[r] * w.y;
                acc[j4 * 4 + 2] += va[r] * w.z;
                acc[j4 * 4 + 3] += va[r] * w.w;
            }
        }
    }
    float p = b2v;
#pragma unroll
    for (int j = 0; j < DD; j++) p += fmaxf(acc[j], 0.f) * s_w2[j];
    out[e] = p;
}

extern "C" void kernel_launch(void* const* d_in, const int* in_sizes, int n_in,
                              void* d_out, int out_size, void* d_ws, size_t ws_size,
                              hipStream_t stream) {
    const int E = in_sizes[0] / 2;
    const int N = in_sizes[2] / DD;

    const int* src = (const int*)d_in[0];
    const int* dst = src + E;
    const float* edge_attr = (const float*)d_in[1];
    const float* node_emb = (const float*)d_in[2];
    const float* sage1_wl = (const float*)d_in[3];
    const float* sage1_bl = (const float*)d_in[4];
    const float* sage1_wr = (const float*)d_in[5];
    const float* sage2_wl = (const float*)d_in[6];
    const float* sage2_bl = (const float*)d_in[7];
    const float* sage2_wr = (const float*)d_in[8];
    const float* gat_w = (const float*)d_in[9];
    const float* gat_att_src = (const float*)d_in[10];
    const float* gat_att_dst = (const float*)d_in[11];
    const float* gat_bias = (const float*)d_in[12];
    const float* mlp_w1 = (const float*)d_in[13];
    const float* mlp_b1 = (const float*)d_in[14];
    const float* mlp_w2 = (const float*)d_in[15];
    const float* mlp_b2 = (const float*)d_in[16];
    float* out = (float*)d_out;

    // Workspace layout (256B-aligned chunks)
    char* ws = (char*)d_ws;
    size_t off = 0;
    auto alloc = [&](size_t bytes) {
        char* p = ws + off;
        off = (off + bytes + 255) & ~(size_t)255;
        return p;
    };
    int* deg = (int*)alloc((size_t)N * 4);
    int* rowptr = (int*)alloc((size_t)(N + 1) * 4);
    int* blockSums = (int*)alloc(128 * 4);
    int* soff = (int*)alloc((size_t)E * 4);
    int* csr_dst = (int*)alloc((size_t)E * 4);
    __half2* ews = (__half2*)alloc((size_t)E * 4);
    __half* x0h = (__half*)alloc((size_t)N * DD * 2);
    __half* x1h = (__half*)alloc((size_t)N * DD * 2);
    __half* x2h = (__half*)alloc((size_t)N * DD * 2);
    float2* a_s = (float2*)alloc((size_t)N * 8);
    float2* a_d = (float2*)alloc((size_t)N * 8);
    float4* c4 = (float4*)alloc(DD * 16);
    __half* Ps = (__half*)alloc((size_t)N * DD * 2);
    __half* Pd = (__half*)alloc((size_t)N * DD * 2);

    const int BS = 256;
    const int gE = (E + BS - 1) / BS;
    const int gN32 = (N * 32 + BS - 1) / BS;
    const int gN1 = (N + BS - 1) / BS;
    const int NB = (N + 1023) / 1024;

    // ---- CSR build ----
    hipMemsetAsync(deg, 0, (size_t)N * sizeof(int), stream);
    hist_k<<<gE, BS, 0, stream>>>(dst, deg, E);
    scan1_k<<<NB, 256, 0, stream>>>(deg, rowptr, blockSums, N);
    scan2_k<<<1, 128, 0, stream>>>(blockSums, rowptr + N, NB);
    scan3_k<<<gN1, BS, 0, stream>>>(rowptr, blockSums, N);
    hipMemsetAsync(deg, 0, (size_t)N * sizeof(int), stream);
    fill_k<<<gE, BS, 0, stream>>>(src, dst, rowptr, deg, soff, csr_dst, E);

    // ---- fp16 input conversion ----
    cvt_k<<<gN32, BS, 0, stream>>>(node_emb, x0h, N * DD);

    // ---- SAGE layers ----
    sage_fused16<<<gN32, BS, 0, stream>>>(x0h, rowptr, soff, sage1_wl, sage1_bl, sage1_wr,
                                          x1h, N);
    sage_fused16<<<gN32, BS, 0, stream>>>(x1h, rowptr, soff, sage2_wl, sage2_bl, sage2_wr,
                                          x2h, N);

    // ---- GAT (+ fused mlp-pre) ----
    prep_c_k<<<1, 64, 0, stream>>>(gat_w, gat_att_src, gat_att_dst, c4);
    gat_scores_v2<<<gN1, BS, 0, stream>>>(x2h, c4, a_s, a_d, N);
    edge_w_k<<<gE, BS, 0, stream>>>(soff, csr_dst, a_s, a_d, ews, E);
    gat_agg_v6<<<gN32, BS, 0, stream>>>(x2h, a_s, a_d, rowptr, soff, ews, gat_w, gat_bias,
                                        mlp_w1, mlp_b1, Ps, Pd, N);

    // ---- Edge MLP ----
    edge_mlp_v3<<<gE, BS, 0, stream>>>(Ps, Pd, edge_attr, src, dst,
                                       mlp_w1 + 2 * DD * DD, mlp_w2, mlp_b2, out, E);
}

// Round 9
// 541.476 us; speedup vs baseline: 2.2144x; 1.0317x over previous
//
#include <hip/hip_runtime.h>
#include <hip/hip_fp16.h>

// GraphSAGE_GAT: SAGE(mean)x2 -> GAT(2 heads, softmax) -> edge MLP
// N=100000, E=1600000, D=32, H=2, EF=16.
// R9: kill half of fill_k's scatter-write amplification (155MB writes for
//     12.8MB payload): drop csr_dst entirely; edge weights computed
//     node-parallel (d = n implicit from CSR range). fill_k scatters only
//     soff (one 4B store/edge, nontemporal).

#define DD 32
#define HH 2
#define EFF 16

__device__ __forceinline__ float lrelu(float x) { return x > 0.f ? x : 0.2f * x; }

// ---- CSR build: histogram of dst ----
__global__ void hist_k(const int* __restrict__ dst, int* __restrict__ deg, int E) {
    int e = blockIdx.x * blockDim.x + threadIdx.x;
    if (e < E) atomicAdd(&deg[dst[e]], 1);
}

// ---- scan phase 1: per-1024-chunk exclusive scan + chunk totals ----
__global__ void scan1_k(const int* __restrict__ deg, int* __restrict__ rowptr,
                        int* __restrict__ blockSums, int N) {
    __shared__ int s_s[256];
    int blk = blockIdx.x, t = threadIdx.x;
    int base = blk * 1024 + t * 4;
    int v[4];
    int s = 0;
#pragma unroll
    for (int i = 0; i < 4; i++) {
        v[i] = (base + i < N) ? deg[base + i] : 0;
        s += v[i];
    }
    s_s[t] = s;
    __syncthreads();
    for (int off = 1; off < 256; off <<= 1) {
        int x = (t >= off) ? s_s[t - off] : 0;
        __syncthreads();
        s_s[t] += x;
        __syncthreads();
    }
    int excl = s_s[t] - s;
#pragma unroll
    for (int i = 0; i < 4; i++) {
        if (base + i < N) rowptr[base + i] = excl;
        excl += v[i];
    }
    if (t == 255) blockSums[blk] = s_s[255];
}

// ---- scan phase 2: scan the chunk totals (<=128 chunks) ----
__global__ void scan2_k(int* __restrict__ blockSums, int* __restrict__ rowptrN, int NB) {
    __shared__ int s_s[128];
    int t = threadIdx.x;
    int v = (t < NB) ? blockSums[t] : 0;
    s_s[t] = v;
    __syncthreads();
    for (int off = 1; off < 128; off <<= 1) {
        int x = (t >= off) ? s_s[t - off] : 0;
        __syncthreads();
        s_s[t] += x;
        __syncthreads();
    }
    if (t < NB) blockSums[t] = s_s[t] - v;  // exclusive
    if (t == 127) *rowptrN = s_s[127];      // total = E
}

// ---- scan phase 3: add chunk offsets ----
__global__ void scan3_k(int* __restrict__ rowptr, const int* __restrict__ blockSums, int N) {
    int i = blockIdx.x * blockDim.x + threadIdx.x;
    if (i < N) rowptr[i] += blockSums[i >> 10];
}

// ---- CSR build: scatter byte offsets (src*64) into per-dst buckets ----
// single 4B nontemporal store per edge (csr_dst eliminated: R8 showed 155MB
// WRITE_SIZE = 12x amplification from two scattered 4B stores per edge)
__global__ void fill_k(const int* __restrict__ src, const int* __restrict__ dst,
                       const int* __restrict__ rowptr, int* __restrict__ fill,
                       int* __restrict__ soff, int E) {
    int e = blockIdx.x * blockDim.x + threadIdx.x;
    if (e >= E) return;
    int d = dst[e];
    int pos = rowptr[d] + atomicAdd(&fill[d], 1);
    __builtin_nontemporal_store(src[e] * 64, &soff[pos]);
}

// ---- convert fp32 -> fp16 ----
__global__ void cvt_k(const float* __restrict__ in, __half* __restrict__ out, int n) {
    int i = blockIdx.x * blockDim.x + threadIdx.x;
    if (i < n) out[i] = __float2half(in[i]);
}

// ---- SAGE fused: gather-mean + lin_l + lin_r + relu -> fp16 (bounded) ----
// one 32-lane group per node
__global__ void sage_fused16(const __half* __restrict__ x, const int* __restrict__ rowptr,
                             const int* __restrict__ soff, const float* __restrict__ wl,
                             const float* __restrict__ bl, const float* __restrict__ wr,
                             __half* __restrict__ out, int N) {
    __shared__ float s_wl[DD * DD];
    __shared__ float s_wr[DD * DD];
    __shared__ float s_b[DD];
    for (int i = threadIdx.x; i < DD * DD; i += blockDim.x) {
        s_wl[i] = wl[i];
        s_wr[i] = wr[i];
    }
    if (threadIdx.x < DD) s_b[threadIdx.x] = bl[threadIdx.x];
    __syncthreads();
    int gid = blockIdx.x * blockDim.x + threadIdx.x;
    int n = gid >> 5;
    if (n >= N) return;
    int k = gid & 31;
    int lo = rowptr[n], hi = rowptr[n + 1];
    const char* xb = (const char*)x;
    float a0 = 0.f, a1 = 0.f, a2 = 0.f, a3 = 0.f;
    int j = lo;
    for (; j + 3 < hi; j += 4) {
        int o0 = soff[j], o1 = soff[j + 1], o2 = soff[j + 2], o3 = soff[j + 3];
        a0 += __half2float(*(const __half*)(xb + o0 + k * 2));
        a1 += __half2float(*(const __half*)(xb + o1 + k * 2));
        a2 += __half2float(*(const __half*)(xb + o2 + k * 2));
        a3 += __half2float(*(const __half*)(xb + o3 + k * 2));
    }
    for (; j < hi; j++) a0 += __half2float(*(const __half*)(xb + soff[j] + k * 2));
    float mean = ((a0 + a1) + (a2 + a3)) / fmaxf((float)(hi - lo), 1.0f);
    float xv = __half2float(x[n * DD + k]);
    float o = s_b[k];
#pragma unroll
    for (int i = 0; i < DD; i++) {
        o += __shfl(mean, i, 32) * s_wl[i * DD + k];
        o += __shfl(xv, i, 32) * s_wr[i * DD + k];
    }
    out[n * DD + k] = __float2half(fmaxf(o, 0.f));
}

// ---- c_s/c_d precompute: c4[i] = (W att_src)[i,h], (W att_dst)[i,h] ----
__global__ void prep_c_k(const float* __restrict__ w, const float* __restrict__ att_src,
                         const float* __restrict__ att_dst, float4* __restrict__ c4) {
    int i = threadIdx.x;
    if (i >= DD) return;
    float cs0 = 0.f, cs1 = 0.f, cd0 = 0.f, cd1 = 0.f;
    for (int d = 0; d < DD; d++) {
        float w0 = w[i * (HH * DD) + d], w1 = w[i * (HH * DD) + DD + d];
        cs0 += w0 * att_src[d];
        cs1 += w1 * att_src[DD + d];
        cd0 += w0 * att_dst[d];
        cd1 += w1 * att_dst[DD + d];
    }
    c4[i] = make_float4(cs0, cs1, cd0, cd1);
}

// ---- GAT scores: thread-per-node dot products against c_s/c_d (bounded) ----
__global__ void gat_scores_v2(const __half* __restrict__ x2, const float4* __restrict__ c4,
                              float2* __restrict__ a_s, float2* __restrict__ a_d, int N) {
    __shared__ float4 s_c[DD];
    if (threadIdx.x < DD) s_c[threadIdx.x] = c4[threadIdx.x];
    __syncthreads();
    int n = blockIdx.x * blockDim.x + threadIdx.x;
    if (n >= N) return;
    const __half2* xr = (const __half2*)(x2 + (size_t)n * DD);
    float as0 = 0.f, as1 = 0.f, ad0 = 0.f, ad1 = 0.f;
#pragma unroll
    for (int i2 = 0; i2 < 16; i2++) {
        float2 f = __half22float2(xr[i2]);
        float4 ca = s_c[i2 * 2], cb = s_c[i2 * 2 + 1];
        as0 += f.x * ca.x + f.y * cb.x;
        as1 += f.x * ca.y + f.y * cb.y;
        ad0 += f.x * ca.z + f.y * cb.z;
        ad1 += f.x * ca.w + f.y * cb.w;
    }
    a_s[n] = make_float2(as0, as1);
    a_d[n] = make_float2(ad0, ad1);
}

// ---- per-edge softmax weights, node-parallel (d = n implicit) ----
// one 32-lane group per node; lanes stride the node's CSR range;
// ews stores are contiguous within the range
__global__ void edge_w_v2(const int* __restrict__ rowptr, const int* __restrict__ soff,
                          const float2* __restrict__ a_s, const float2* __restrict__ a_d,
                          __half2* __restrict__ ews, int N) {
    int gid = blockIdx.x * blockDim.x + threadIdx.x;
    int n = gid >> 5;
    if (n >= N) return;
    int kk = gid & 31;
    int lo = rowptr[n], hi = rowptr[n + 1];
    float2 ad = a_d[n];
    const char* asb = (const char*)a_s;
    for (int j = lo + kk; j < hi; j += 32) {
        float2 as = *(const float2*)(asb + (soff[j] >> 3));  // s*8
        float w0 = __expf(lrelu(as.x + ad.x));
        float w1 = __expf(lrelu(as.y + ad.y));
        ews[j] = __floats2half2_rn(w0, w1);
    }
}

// ---- GAT aggregate v6: 32 lanes/node (2 nodes/wave), bounded grid;
//      one gather serves both heads -> W transform -> head-mean+bias+relu
//      -> fused mlp-pre ----
__global__ void gat_agg_v6(const __half* __restrict__ x2, const float2* __restrict__ a_s,
                           const float2* __restrict__ a_d, const int* __restrict__ rowptr,
                           const int* __restrict__ soff, const __half2* __restrict__ ews,
                           const float* __restrict__ gw, const float* __restrict__ bias,
                           const float* __restrict__ w1, const float* __restrict__ b1,
                           __half* __restrict__ Ps, __half* __restrict__ Pd, int N) {
    __shared__ float s_gw[DD * HH * DD];  // gat W: 32 x 64
    __shared__ float s_w1[2 * DD * DD];   // mlp w1 rows 0..63
    __shared__ float s_b1[DD];
    __shared__ float s_bias[DD];
    int t = threadIdx.x;
    for (int i = t; i < DD * HH * DD; i += blockDim.x) s_gw[i] = gw[i];
    for (int i = t; i < 2 * DD * DD; i += blockDim.x) s_w1[i] = w1[i];
    if (t < DD) {
        s_b1[t] = b1[t];
        s_bias[t] = bias[t];
    }
    __syncthreads();
    int gid = blockIdx.x * blockDim.x + t;
    int n = gid >> 5;
    if (n >= N) return;
    int kk = gid & 31;
    const char* xb = (const char*)x2;
    int lo = rowptr[n], hi = rowptr[n + 1];
    float2 as = a_s[n], ad = a_d[n];
    float ws0 = __expf(lrelu(as.x + ad.x));
    float ws1 = __expf(lrelu(as.y + ad.y));
    float xvs = __half2float(x2[n * DD + kk]);
    float den0 = ws0, den1 = ws1;
    float y0a = ws0 * xvs, y1a = ws1 * xvs;
    float y0b = 0.f, y1b = 0.f;
    int j = lo;
    for (; j + 3 < hi; j += 4) {
        int o0 = soff[j], o1 = soff[j + 1], o2 = soff[j + 2], o3 = soff[j + 3];
        float2 e0 = __half22float2(ews[j]);
        float2 e1 = __half22float2(ews[j + 1]);
        float2 e2 = __half22float2(ews[j + 2]);
        float2 e3 = __half22float2(ews[j + 3]);
        float xv0 = __half2float(*(const __half*)(xb + o0 + kk * 2));
        float xv1 = __half2float(*(const __half*)(xb + o1 + kk * 2));
        float xv2 = __half2float(*(const __half*)(xb + o2 + kk * 2));
        float xv3 = __half2float(*(const __half*)(xb + o3 + kk * 2));
        den0 += (e0.x + e1.x) + (e2.x + e3.x);
        den1 += (e0.y + e1.y) + (e2.y + e3.y);
        y0a += e0.x * xv0 + e2.x * xv2;
        y1a += e0.y * xv0 + e2.y * xv2;
        y0b += e1.x * xv1 + e3.x * xv3;
        y1b += e1.y * xv1 + e3.y * xv3;
    }
    for (; j < hi; j++) {
        int o0 = soff[j];
        float2 e0 = __half22float2(ews[j]);
        float xv0 = __half2float(*(const __half*)(xb + o0 + kk * 2));
        den0 += e0.x;
        den1 += e0.y;
        y0a += e0.x * xv0;
        y1a += e0.y * xv0;
    }
    float u0 = (y0a + y0b) / (den0 + 1e-16f);
    float u1 = (y1a + y1b) / (den1 + 1e-16f);
    // out[kk] = 0.5*(u0 @ Wg[:,kk] + u1 @ Wg[:,32+kk]) + bias, relu
    float o = 0.f;
#pragma unroll
    for (int i = 0; i < DD; i++) {
        float c0 = __shfl(u0, i, 32), c1 = __shfl(u1, i, 32);
        o += c0 * s_gw[i * (HH * DD) + kk] + c1 * s_gw[i * (HH * DD) + DD + kk];
    }
    o = fmaxf(0.5f * o + s_bias[kk], 0.f);
    // fused mlp-pre: Ps (rows 0..31 of w1, +b1), Pd (rows 32..63)
    float ps = s_b1[kk], pd = 0.f;
#pragma unroll
    for (int i = 0; i < DD; i++) {
        float oi = __shfl(o, i, 32);
        ps += oi * s_w1[i * DD + kk];
        pd += oi * s_w1[(DD + i) * DD + kk];
    }
    Ps[n * DD + kk] = __float2half(ps);
    Pd[n * DD + kk] = __float2half(pd);
}

// ---- Edge MLP: acc = Ps[s] + Pd[d] + W1e*ea; out = relu(acc) . w2 + b2 ----
// one thread per edge, straight-line body
__device__ __forceinline__ void add_half_row(const __half* __restrict__ row, float acc[DD]) {
    const uint4* r4 = (const uint4*)row;
#pragma unroll
    for (int c = 0; c < 4; c++) {
        uint4 u = r4[c];
        unsigned uu[4] = {u.x, u.y, u.z, u.w};
#pragma unroll
        for (int t = 0; t < 4; t++) {
            __half2 h2 = *reinterpret_cast<const __half2*>(&uu[t]);
            float2 f = __half22float2(h2);
            acc[c * 8 + t * 2 + 0] += f.x;
            acc[c * 8 + t * 2 + 1] += f.y;
        }
    }
}

__global__ void edge_mlp_v3(const __half* __restrict__ Ps, const __half* __restrict__ Pd,
                            const float* __restrict__ eattr, const int* __restrict__ src,
                            const int* __restrict__ dst, const float* __restrict__ w1e,
                            const float* __restrict__ w2, const float* __restrict__ b2,
                            float* __restrict__ out, int E) {
    __shared__ float s_we[EFF * DD];  // rows 64..79 of w1
    __shared__ float s_w2[DD];
    for (int i = threadIdx.x; i < EFF * DD; i += blockDim.x) s_we[i] = w1e[i];
    if (threadIdx.x < DD) s_w2[threadIdx.x] = w2[threadIdx.x];
    __syncthreads();
    int e = blockIdx.x * blockDim.x + threadIdx.x;
    if (e >= E) return;
    float b2v = b2[0];
    int s = src[e], d = dst[e];
    float acc[DD] = {};
    add_half_row(Ps + (size_t)s * DD, acc);
    add_half_row(Pd + (size_t)d * DD, acc);
    const float4* ea4 = (const float4*)(eattr + (size_t)e * EFF);
#pragma unroll
    for (int c = 0; c < 4; c++) {
        float4 v = ea4[c];
        const float va[4] = {v.x, v.y, v.z, v.w};
#pragma unroll
        for (int r = 0; r < 4; r++) {
#pragma unroll
            for (int j4 = 0; j4 < 8; j4++) {
                const float4 w = *(const float4*)(s_we + (c * 4 + r) * DD + j4 * 4);
                acc[j4 * 4 + 0] += va[r] * w.x;
                acc[j4 * 4 + 1] += va[r] * w.y;
                acc[j4 * 4 + 2] += va[r] * w.z;
                acc[j4 * 4 + 3] += va[r] * w.w;
            }
        }
    }
    float p = b2v;
#pragma unroll
    for (int j = 0; j < DD; j++) p += fmaxf(acc[j], 0.f) * s_w2[j];
    out[e] = p;
}

extern "C" void kernel_launch(void* const* d_in, const int* in_sizes, int n_in,
                              void* d_out, int out_size, void* d_ws, size_t ws_size,
                              hipStream_t stream) {
    const int E = in_sizes[0] / 2;
    const int N = in_sizes[2] / DD;

    const int* src = (const int*)d_in[0];
    const int* dst = src + E;
    const float* edge_attr = (const float*)d_in[1];
    const float* node_emb = (const float*)d_in[2];
    const float* sage1_wl = (const float*)d_in[3];
    const float* sage1_bl = (const float*)d_in[4];
    const float* sage1_wr = (const float*)d_in[5];
    const float* sage2_wl = (const float*)d_in[6];
    const float* sage2_bl = (const float*)d_in[7];
    const float* sage2_wr = (const float*)d_in[8];
    const float* gat_w = (const float*)d_in[9];
    const float* gat_att_src = (const float*)d_in[10];
    const float* gat_att_dst = (const float*)d_in[11];
    const float* gat_bias = (const float*)d_in[12];
    const float* mlp_w1 = (const float*)d_in[13];
    const float* mlp_b1 = (const float*)d_in[14];
    const float* mlp_w2 = (const float*)d_in[15];
    const float* mlp_b2 = (const float*)d_in[16];
    float* out = (float*)d_out;

    // Workspace layout (256B-aligned chunks)
    char* ws = (char*)d_ws;
    size_t off = 0;
    auto alloc = [&](size_t bytes) {
        char* p = ws + off;
        off = (off + bytes + 255) & ~(size_t)255;
        return p;
    };
    int* deg = (int*)alloc((size_t)N * 4);
    int* rowptr = (int*)alloc((size_t)(N + 1) * 4);
    int* blockSums = (int*)alloc(128 * 4);
    int* soff = (int*)alloc((size_t)E * 4);
    __half2* ews = (__half2*)alloc((size_t)E * 4);
    __half* x0h = (__half*)alloc((size_t)N * DD * 2);
    __half* x1h = (__half*)alloc((size_t)N * DD * 2);
    __half* x2h = (__half*)alloc((size_t)N * DD * 2);
    float2* a_s = (float2*)alloc((size_t)N * 8);
    float2* a_d = (float2*)alloc((size_t)N * 8);
    float4* c4 = (float4*)alloc(DD * 16);
    __half* Ps = (__half*)alloc((size_t)N * DD * 2);
    __half* Pd = (__half*)alloc((size_t)N * DD * 2);

    const int BS = 256;
    const int gE = (E + BS - 1) / BS;
    const int gN32 = (N * 32 + BS - 1) / BS;
    const int gN1 = (N + BS - 1) / BS;
    const int NB = (N + 1023) / 1024;

    // ---- CSR build ----
    hipMemsetAsync(deg, 0, (size_t)N * sizeof(int), stream);
    hist_k<<<gE, BS, 0, stream>>>(dst, deg, E);
    scan1_k<<<NB, 256, 0, stream>>>(deg, rowptr, blockSums, N);
    scan2_k<<<1, 128, 0, stream>>>(blockSums, rowptr + N, NB);
    scan3_k<<<gN1, BS, 0, stream>>>(rowptr, blockSums, N);
    hipMemsetAsync(deg, 0, (size_t)N * sizeof(int), stream);
    fill_k<<<gE, BS, 0, stream>>>(src, dst, rowptr, deg, soff, E);

    // ---- fp16 input conversion ----
    cvt_k<<<gN32, BS, 0, stream>>>(node_emb, x0h, N * DD);

    // ---- SAGE layers ----
    sage_fused16<<<gN32, BS, 0, stream>>>(x0h, rowptr, soff, sage1_wl, sage1_bl, sage1_wr,
                                          x1h, N);
    sage_fused16<<<gN32, BS, 0, stream>>>(x1h, rowptr, soff, sage2_wl, sage2_bl, sage2_wr,
                                          x2h, N);

    // ---- GAT (+ fused mlp-pre) ----
    prep_c_k<<<1, 64, 0, stream>>>(gat_w, gat_att_src, gat_att_dst, c4);
    gat_scores_v2<<<gN1, BS, 0, stream>>>(x2h, c4, a_s, a_d, N);
    edge_w_v2<<<gN32, BS, 0, stream>>>(rowptr, soff, a_s, a_d, ews, N);
    gat_agg_v6<<<gN32, BS, 0, stream>>>(x2h, a_s, a_d, rowptr, soff, ews, gat_w, gat_bias,
                                        mlp_w1, mlp_b1, Ps, Pd, N);

    // ---- Edge MLP ----
    edge_mlp_v3<<<gE, BS, 0, stream>>>(Ps, Pd, edge_attr, src, dst,
                                       mlp_w1 + 2 * DD * DD, mlp_w2, mlp_b2, out, E);
}